// Round 2
// baseline (1021.051 us; speedup 1.0000x reference)
//
#include <hip/hip_runtime.h>
#include <math.h>

#define B 64
#define S 512
#define E 128
#define NT 10

// Rotation by d within each quad of lanes (lane j gets value from lane (j+d)&3),
// via __shfl with absolute source lane — executed unconditionally by all lanes.
__device__ __forceinline__ double rotd(double x, int d) {
    int lane = threadIdx.x;              // k2 blocks are exactly one wave (64)
    int src = (lane & ~3) | ((lane + d) & 3);
    return __shfl(x, src, 64);
}

// ---------------------------------------------------------------------------
// k1: Xproj[p][q] = sum_e emb[x[p]][e] * W_g[e][j] + b_g[j] + th_g[j]
//     p = b*S + s, q = j*4 + g  (g = gate: 0=f,1=i,2=u,3=o; j = wire)
//     f64 accumulation, stored as f32.
// ---------------------------------------------------------------------------
__global__ void __launch_bounds__(256) k1_xproj(
        const int* __restrict__ x, const float* __restrict__ emb,
        const float* __restrict__ Wf, const float* __restrict__ bf, const float* __restrict__ thf,
        const float* __restrict__ Wi, const float* __restrict__ bi, const float* __restrict__ thi,
        const float* __restrict__ Wu, const float* __restrict__ bu, const float* __restrict__ thu,
        const float* __restrict__ Wo, const float* __restrict__ bo, const float* __restrict__ tho,
        float* __restrict__ Xproj) {
    __shared__ __align__(16) float Wl[16][132];
    __shared__ double bl[16];
    const int tid = threadIdx.x;
    {
        const float* Wm[4] = {Wf, Wi, Wu, Wo};
        for (int idx = tid; idx < 16 * E; idx += 256) {
            int e = idx >> 4, q = idx & 15;
            int g = q & 3, j = q >> 2;
            Wl[q][e] = Wm[g][e * 4 + j];
        }
        if (tid < 16) {
            const float* bm[4] = {bf, bi, bu, bo};
            const float* tm[4] = {thf, thi, thu, tho};
            int g = tid & 3, j = tid >> 2;
            bl[tid] = (double)bm[g][j] + (double)tm[g][j];
        }
    }
    __syncthreads();
    const int T = blockIdx.x * 256 + tid;
    const int p = T >> 4, q = T & 15;
    if (p >= B * S) return;
    const float* row = emb + (size_t)x[p] * E;
    double acc = bl[q];
    #pragma unroll
    for (int e = 0; e < E; e += 4) {
        float4 wv = *(const float4*)(&Wl[q][e]);
        float4 ev = *(const float4*)(row + e);
        acc += (double)ev.x * (double)wv.x + (double)ev.y * (double)wv.y
             + (double)ev.z * (double)wv.z + (double)ev.w * (double)wv.w;
    }
    Xproj[(size_t)p * 16 + q] = (float)acc;
}

// ---------------------------------------------------------------------------
// k2: sequential LSTM recurrence in FULL f64 with exact libm transcendentals.
// 4 lanes per batch element (lane j = wire j).
// Quantum layer reduced analytically to products of cos(pre):
//   Z0=c1c2c3, Z1=c0c1, Z2=c0c1c2, Z3=c0c1c2c3
// hbuf layout: [B][S][4] (f32)
// ---------------------------------------------------------------------------
__global__ void __launch_bounds__(64) k2_recur(
        const float* __restrict__ Xproj,
        const float* __restrict__ Wf, const float* __restrict__ Wi,
        const float* __restrict__ Wu, const float* __restrict__ Wo,
        float* __restrict__ hbuf) {
    const int lane = threadIdx.x;
    const int T = blockIdx.x * 64 + lane;
    const int b = T >> 2, j = T & 3;

    // recurrent weights, pre-permuted to rotated hx register order:
    // hx register d holds hx_{(j+d)&3}
    const float* Wm[4] = {Wf, Wi, Wu, Wo};
    double w[4][4];
    #pragma unroll
    for (int g = 0; g < 4; ++g)
        #pragma unroll
        for (int d = 0; d < 4; ++d)
            w[g][d] = (double)Wm[g][(E + ((j + d) & 3)) * 4 + j];

    // inclusion masks for the cosine products (lane-relative rotated regs):
    // own=c_j, r1=c_{j+1}, r2=c_{j+2}, r3=c_{j+3} (mod 4); r3 always included.
    const bool m_own = (j != 0);
    const bool m_r1  = (j == 0) || (j == 3);
    const bool m_r2  = (j != 1);

    double hx0 = 0.0, hx1 = 0.0, hx2 = 0.0, hx3 = 0.0, cx = 0.0;

    const float4* xp4 = (const float4*)Xproj + (size_t)b * S * 4 + j; // [p*4+j]
    float* hout = hbuf + (size_t)b * S * 4 + j;

    for (int t = 0; t < S; ++t) {
        float4 xp = xp4[(size_t)t * 4];

        double pre0 = (double)xp.x + w[0][0]*hx0 + w[0][1]*hx1 + w[0][2]*hx2 + w[0][3]*hx3;
        double pre1 = (double)xp.y + w[1][0]*hx0 + w[1][1]*hx1 + w[1][2]*hx2 + w[1][3]*hx3;
        double pre2 = (double)xp.z + w[2][0]*hx0 + w[2][1]*hx1 + w[2][2]*hx2 + w[2][3]*hx3;
        double pre3 = (double)xp.w + w[3][0]*hx0 + w[3][1]*hx1 + w[3][2]*hx2 + w[3][3]*hx3;

        double c0 = cos(pre0);
        double c1 = cos(pre1);
        double c2 = cos(pre2);
        double c3 = cos(pre3);

        // shuffles executed unconditionally (no divergence around cross-lane ops)
        double a01 = rotd(c0, 1), a02 = rotd(c0, 2), a03 = rotd(c0, 3);
        double a11 = rotd(c1, 1), a12 = rotd(c1, 2), a13 = rotd(c1, 3);
        double a21 = rotd(c2, 1), a22 = rotd(c2, 2), a23 = rotd(c2, 3);
        double a31 = rotd(c3, 1), a32 = rotd(c3, 2), a33 = rotd(c3, 3);

        double z0 = (m_own ? c0 : 1.0) * (m_r1 ? a01 : 1.0) * (m_r2 ? a02 : 1.0) * a03;
        double z1 = (m_own ? c1 : 1.0) * (m_r1 ? a11 : 1.0) * (m_r2 ? a12 : 1.0) * a13;
        double z2 = (m_own ? c2 : 1.0) * (m_r1 ? a21 : 1.0) * (m_r2 ? a22 : 1.0) * a23;
        double z3 = (m_own ? c3 : 1.0) * (m_r1 ? a31 : 1.0) * (m_r2 ? a32 : 1.0) * a33;

        double f  = 1.0 / (1.0 + exp(-z0));
        double i_ = 1.0 / (1.0 + exp(-z1));
        double u  = tanh(z2);
        double o  = 1.0 / (1.0 + exp(-z3));

        cx = f * cx + i_ * u;
        double h = o * tanh(cx);

        hout[(size_t)t * 4] = (float)h;

        hx0 = h;
        hx1 = rotd(h, 1);
        hx2 = rotd(h, 2);
        hx3 = rotd(h, 3);
    }
}

// ---------------------------------------------------------------------------
// k3: logits = hx @ Wt + bt, then log_softmax over the 10 tags, f64 internals.
// ---------------------------------------------------------------------------
__global__ void __launch_bounds__(256) k3_head(
        const float* __restrict__ hbuf, const float* __restrict__ Wt,
        const float* __restrict__ bt, float* __restrict__ out) {
    const int pos = blockIdx.x * 256 + threadIdx.x;
    if (pos >= B * S) return;
    float4 h = ((const float4*)hbuf)[pos];
    double h0 = h.x, h1 = h.y, h2 = h.z, h3 = h.w;
    double lo[NT];
    double m = -1e300;
    #pragma unroll
    for (int t = 0; t < NT; ++t) {
        lo[t] = (double)bt[t] + h0 * (double)Wt[t] + h1 * (double)Wt[NT + t]
              + h2 * (double)Wt[2 * NT + t] + h3 * (double)Wt[3 * NT + t];
        m = fmax(m, lo[t]);
    }
    double sum = 0.0;
    #pragma unroll
    for (int t = 0; t < NT; ++t) sum += exp(lo[t] - m);
    double lse = m + log(sum);
    float* op = out + (size_t)pos * NT;
    #pragma unroll
    for (int t = 0; t < NT; ++t) op[t] = (float)(lo[t] - lse);
}

extern "C" void kernel_launch(void* const* d_in, const int* in_sizes, int n_in,
                              void* d_out, int out_size, void* d_ws, size_t ws_size,
                              hipStream_t stream) {
    const int*   x   = (const int*)d_in[0];
    const float* emb = (const float*)d_in[1];
    const float* Wf  = (const float*)d_in[2];
    const float* bf  = (const float*)d_in[3];
    const float* thf = (const float*)d_in[4];
    const float* Wi  = (const float*)d_in[5];
    const float* bi  = (const float*)d_in[6];
    const float* thi = (const float*)d_in[7];
    const float* Wu  = (const float*)d_in[8];
    const float* bu  = (const float*)d_in[9];
    const float* thu = (const float*)d_in[10];
    const float* Wo  = (const float*)d_in[11];
    const float* bo  = (const float*)d_in[12];
    const float* tho = (const float*)d_in[13];
    const float* Wt  = (const float*)d_in[14];
    const float* bt  = (const float*)d_in[15];
    float* out = (float*)d_out;

    // workspace: Xproj [B*S*16] f32, then hbuf [B*S*4] f32
    if (ws_size < (size_t)(B * S * 20) * sizeof(float)) return;
    float* Xproj = (float*)d_ws;
    float* hbuf  = Xproj + (size_t)B * S * 16;

    k1_xproj<<<(B * S * 16) / 256, 256, 0, stream>>>(x, emb, Wf, bf, thf, Wi, bi, thi,
                                                     Wu, bu, thu, Wo, bo, tho, Xproj);
    k2_recur<<<(B * 4) / 64, 64, 0, stream>>>(Xproj, Wf, Wi, Wu, Wo, hbuf);
    k3_head<<<(B * S) / 256, 256, 0, stream>>>(hbuf, Wt, bt, out);
}

// Round 5
// 556.487 us; speedup vs baseline: 1.8348x; 1.8348x over previous
//
#include <hip/hip_runtime.h>
#include <math.h>

#define B 64
#define S 512
#define E 128
#define NT 10

// Rotation by d within each quad of lanes (lane j gets value from lane (j+d)&3),
// via __shfl with absolute source lane — executed unconditionally by all lanes.
// (VERIFIED on HW in round 2. DPP variant is under suspicion — do not use yet.)
__device__ __forceinline__ double rotd(double x, int d) {
    int lane = threadIdx.x;              // k2 blocks are exactly one wave (64)
    int src = (lane & ~3) | ((lane + d) & 3);
    return __shfl(x, src, 64);
}

// ---------------------------------------------------------------------------
// Fast f64 transcendentals, branch-free, valid for this problem's ranges.
// cosd: |x| <= ~30 (here <= ~6).  abs err ~7e-11.
// ---------------------------------------------------------------------------
__device__ __forceinline__ double cosd(double x) {
    const double INVPI = 0.31830988618379067154;
    const double PI_HI = 3.1415926535897931160;
    const double PI_LO = 1.2246467991473532072e-16;
    double nd = __builtin_rint(x * INVPI);
    int ni = (int)nd;
    double r = fma(-nd, PI_HI, x);
    r = fma(-nd, PI_LO, r);
    double s = r * r;
    double p = -1.14707455977297245e-11;          // Taylor 1/(2k)! alternating
    p = fma(p, s, 2.08767569878680989e-9);
    p = fma(p, s, -2.75573192239858925e-7);
    p = fma(p, s, 2.48015873015873016e-5);
    p = fma(p, s, -1.38888888888888894e-3);
    p = fma(p, s, 4.16666666666666666e-2);
    p = fma(p, s, -0.5);
    p = fma(p, s, 1.0);
    long long sgn = ((long long)(ni & 1)) << 63;  // (-1)^n
    return __longlong_as_double(__double_as_longlong(p) ^ sgn);
}

// expd: |y| <= ~8 here (n in [-12,12] safe). rel err ~7e-12.
__device__ __forceinline__ double expd(double y) {
    const double LOG2E  = 1.4426950408889634074;
    const double LN2_HI = 0.69314718055994530942;
    const double LN2_LO = 2.3190468138462995584e-17;
    double nd = __builtin_rint(y * LOG2E);
    int ni = (int)nd;
    double r = fma(-nd, LN2_HI, y);
    r = fma(-nd, LN2_LO, r);                      // |r| <= 0.3466
    double p = 2.7557319223985893e-6;             // 1/9!
    p = fma(p, r, 2.4801587301587302e-5);
    p = fma(p, r, 1.9841269841269841e-4);
    p = fma(p, r, 1.3888888888888889e-3);
    p = fma(p, r, 8.3333333333333333e-3);
    p = fma(p, r, 4.1666666666666664e-2);
    p = fma(p, r, 1.6666666666666666e-1);
    p = fma(p, r, 0.5);
    p = fma(p, r, 1.0);
    p = fma(p, r, 1.0);
    long long bits = __double_as_longlong(p) + (((long long)ni) << 52); // *2^n
    return __longlong_as_double(bits);
}

__device__ __forceinline__ double frcp64(double d) {
    double r = __builtin_amdgcn_rcp(d);           // v_rcp_f64
    double e = fma(-d, r, 1.0);
    r = fma(r, e, r);
    e = fma(-d, r, 1.0);
    r = fma(r, e, r);
    return r;
}

__device__ __forceinline__ double sigd(double z) {           // |z| <= 1
    return frcp64(1.0 + expd(-z));
}
__device__ __forceinline__ double tanhd(double x) {          // |x| <= ~4 here
    double ex = expd(x + x);
    return (ex - 1.0) * frcp64(ex + 1.0);
}

// ---------------------------------------------------------------------------
// k1: Xproj[p][q] = sum_e emb[x[p]][e] * W_g[e][j] + b_g[j] + th_g[j]
//     p = b*S + s, q = j*4 + g  (g: 0=f,1=i,2=u,3=o; j = wire)
//     f64 accumulation, stored as f32.  (verbatim from passing round 2)
// ---------------------------------------------------------------------------
__global__ void __launch_bounds__(256) k1_xproj(
        const int* __restrict__ x, const float* __restrict__ emb,
        const float* __restrict__ Wf, const float* __restrict__ bf, const float* __restrict__ thf,
        const float* __restrict__ Wi, const float* __restrict__ bi, const float* __restrict__ thi,
        const float* __restrict__ Wu, const float* __restrict__ bu, const float* __restrict__ thu,
        const float* __restrict__ Wo, const float* __restrict__ bo, const float* __restrict__ tho,
        float* __restrict__ Xproj) {
    __shared__ __align__(16) float Wl[16][132];
    __shared__ double bl[16];
    const int tid = threadIdx.x;
    {
        const float* Wm[4] = {Wf, Wi, Wu, Wo};
        for (int idx = tid; idx < 16 * E; idx += 256) {
            int e = idx >> 4, q = idx & 15;
            int g = q & 3, j = q >> 2;
            Wl[q][e] = Wm[g][e * 4 + j];
        }
        if (tid < 16) {
            const float* bm[4] = {bf, bi, bu, bo};
            const float* tm[4] = {thf, thi, thu, tho};
            int g = tid & 3, j = tid >> 2;
            bl[tid] = (double)bm[g][j] + (double)tm[g][j];
        }
    }
    __syncthreads();
    const int T = blockIdx.x * 256 + tid;
    const int p = T >> 4, q = T & 15;
    if (p >= B * S) return;
    const float* row = emb + (size_t)x[p] * E;
    double acc = bl[q];
    #pragma unroll
    for (int e = 0; e < E; e += 4) {
        float4 wv = *(const float4*)(&Wl[q][e]);
        float4 ev = *(const float4*)(row + e);
        acc += (double)ev.x * (double)wv.x + (double)ev.y * (double)wv.y
             + (double)ev.z * (double)wv.z + (double)ev.w * (double)wv.w;
    }
    Xproj[(size_t)p * 16 + q] = (float)acc;
}

// ---------------------------------------------------------------------------
// k2: sequential LSTM recurrence — round-2 structure verbatim (shfl, no
// prefetch), with ONLY the transcendentals swapped libm -> poly.
//   Z0=c1c2c3, Z1=c0c1, Z2=c0c1c2, Z3=c0c1c2c3  (verified on HW, round 2)
// hbuf layout: [B][S][4] (f32)
// ---------------------------------------------------------------------------
__global__ void __launch_bounds__(64) k2_recur(
        const float* __restrict__ Xproj,
        const float* __restrict__ Wf, const float* __restrict__ Wi,
        const float* __restrict__ Wu, const float* __restrict__ Wo,
        float* __restrict__ hbuf) {
    const int lane = threadIdx.x;
    const int T = blockIdx.x * 64 + lane;
    const int b = T >> 2, j = T & 3;

    // recurrent weights pre-permuted: hx register d holds hx_{(j+d)&3}
    const float* Wm[4] = {Wf, Wi, Wu, Wo};
    double w[4][4];
    #pragma unroll
    for (int g = 0; g < 4; ++g)
        #pragma unroll
        for (int d = 0; d < 4; ++d)
            w[g][d] = (double)Wm[g][(E + ((j + d) & 3)) * 4 + j];

    // inclusion masks (lane-relative rotated regs); r3 always included.
    const bool m_own = (j != 0);
    const bool m_r1  = (j == 0) || (j == 3);
    const bool m_r2  = (j != 1);

    double hx0 = 0.0, hx1 = 0.0, hx2 = 0.0, hx3 = 0.0, cx = 0.0;

    const float4* xp4 = (const float4*)Xproj + (size_t)b * S * 4 + j; // [p*4+j]
    float* hout = hbuf + (size_t)b * S * 4 + j;

    for (int t = 0; t < S; ++t) {
        float4 xp = xp4[(size_t)t * 4];

        double pre0 = (double)xp.x + w[0][0]*hx0 + w[0][1]*hx1 + w[0][2]*hx2 + w[0][3]*hx3;
        double pre1 = (double)xp.y + w[1][0]*hx0 + w[1][1]*hx1 + w[1][2]*hx2 + w[1][3]*hx3;
        double pre2 = (double)xp.z + w[2][0]*hx0 + w[2][1]*hx1 + w[2][2]*hx2 + w[2][3]*hx3;
        double pre3 = (double)xp.w + w[3][0]*hx0 + w[3][1]*hx1 + w[3][2]*hx2 + w[3][3]*hx3;

        double c0 = cosd(pre0);
        double c1 = cosd(pre1);
        double c2 = cosd(pre2);
        double c3 = cosd(pre3);

        // shuffles executed unconditionally (no divergence around cross-lane ops)
        double a01 = rotd(c0, 1), a02 = rotd(c0, 2), a03 = rotd(c0, 3);
        double a11 = rotd(c1, 1), a12 = rotd(c1, 2), a13 = rotd(c1, 3);
        double a21 = rotd(c2, 1), a22 = rotd(c2, 2), a23 = rotd(c2, 3);
        double a31 = rotd(c3, 1), a32 = rotd(c3, 2), a33 = rotd(c3, 3);

        double z0 = (m_own ? c0 : 1.0) * (m_r1 ? a01 : 1.0) * (m_r2 ? a02 : 1.0) * a03;
        double z1 = (m_own ? c1 : 1.0) * (m_r1 ? a11 : 1.0) * (m_r2 ? a12 : 1.0) * a13;
        double z2 = (m_own ? c2 : 1.0) * (m_r1 ? a21 : 1.0) * (m_r2 ? a22 : 1.0) * a23;
        double z3 = (m_own ? c3 : 1.0) * (m_r1 ? a31 : 1.0) * (m_r2 ? a32 : 1.0) * a33;

        double f  = sigd(z0);
        double i_ = sigd(z1);
        double u  = tanhd(z2);
        double o  = sigd(z3);

        cx = f * cx + i_ * u;
        double h = o * tanhd(cx);

        hout[(size_t)t * 4] = (float)h;

        hx0 = h;
        hx1 = rotd(h, 1);
        hx2 = rotd(h, 2);
        hx3 = rotd(h, 3);
    }
}

// ---------------------------------------------------------------------------
// k3: logits = hx @ Wt + bt, then log_softmax over the 10 tags, f64 internals.
// (verbatim from passing round 2)
// ---------------------------------------------------------------------------
__global__ void __launch_bounds__(256) k3_head(
        const float* __restrict__ hbuf, const float* __restrict__ Wt,
        const float* __restrict__ bt, float* __restrict__ out) {
    const int pos = blockIdx.x * 256 + threadIdx.x;
    if (pos >= B * S) return;
    float4 h = ((const float4*)hbuf)[pos];
    double h0 = h.x, h1 = h.y, h2 = h.z, h3 = h.w;
    double lo[NT];
    double m = -1e300;
    #pragma unroll
    for (int t = 0; t < NT; ++t) {
        lo[t] = (double)bt[t] + h0 * (double)Wt[t] + h1 * (double)Wt[NT + t]
              + h2 * (double)Wt[2 * NT + t] + h3 * (double)Wt[3 * NT + t];
        m = fmax(m, lo[t]);
    }
    double sum = 0.0;
    #pragma unroll
    for (int t = 0; t < NT; ++t) sum += exp(lo[t] - m);
    double lse = m + log(sum);
    float* op = out + (size_t)pos * NT;
    #pragma unroll
    for (int t = 0; t < NT; ++t) op[t] = (float)(lo[t] - lse);
}

extern "C" void kernel_launch(void* const* d_in, const int* in_sizes, int n_in,
                              void* d_out, int out_size, void* d_ws, size_t ws_size,
                              hipStream_t stream) {
    const int*   x   = (const int*)d_in[0];
    const float* emb = (const float*)d_in[1];
    const float* Wf  = (const float*)d_in[2];
    const float* bf  = (const float*)d_in[3];
    const float* thf = (const float*)d_in[4];
    const float* Wi  = (const float*)d_in[5];
    const float* bi  = (const float*)d_in[6];
    const float* thi = (const float*)d_in[7];
    const float* Wu  = (const float*)d_in[8];
    const float* bu  = (const float*)d_in[9];
    const float* thu = (const float*)d_in[10];
    const float* Wo  = (const float*)d_in[11];
    const float* bo  = (const float*)d_in[12];
    const float* tho = (const float*)d_in[13];
    const float* Wt  = (const float*)d_in[14];
    const float* bt  = (const float*)d_in[15];
    float* out = (float*)d_out;

    // workspace: Xproj [B*S*16] f32, then hbuf [B*S*4] f32
    if (ws_size < (size_t)(B * S * 20) * sizeof(float)) return;
    float* Xproj = (float*)d_ws;
    float* hbuf  = Xproj + (size_t)B * S * 16;

    k1_xproj<<<(B * S * 16) / 256, 256, 0, stream>>>(x, emb, Wf, bf, thf, Wi, bi, thi,
                                                     Wu, bu, thu, Wo, bo, tho, Xproj);
    k2_recur<<<(B * 4) / 64, 64, 0, stream>>>(Xproj, Wf, Wi, Wu, Wo, hbuf);
    k3_head<<<(B * S) / 256, 256, 0, stream>>>(hbuf, Wt, bt, out);
}

// Round 6
// 320.151 us; speedup vs baseline: 3.1893x; 1.7382x over previous
//
#include <hip/hip_runtime.h>
#include <math.h>

#define B 64
#define S 512
#define E 128
#define NT 10

// Rotation by d within each quad of lanes (lane j gets value from lane (j+d)&3),
// via __shfl with absolute source lane.
// RULE (HW-verified rounds 1/2/4/5): cross-lane ops MUST be executed
// unconditionally by all lanes — hoist, then mask. Never inside ternaries.
__device__ __forceinline__ float rotf(float x, int d) {
    int lane = threadIdx.x;              // k2 blocks are exactly one wave (64)
    int src = (lane & ~3) | ((lane + d) & 3);
    return __shfl(x, src, 64);
}

__device__ __forceinline__ float frcp(float x) { return __builtin_amdgcn_rcpf(x); }
__device__ __forceinline__ float fsigmoid(float x) { return frcp(1.0f + __expf(-x)); }
__device__ __forceinline__ float ftanh(float x) { return 1.0f - 2.0f * frcp(1.0f + __expf(2.0f * x)); }

// ---------------------------------------------------------------------------
// k1: Xproj[p][q] = sum_e emb[x[p]][e] * W_g[e][j] + b_g[j] + th_g[j]
//     p = b*S + s, q = j*4 + g  (g: 0=f,1=i,2=u,3=o; j = wire). all-f32
//     (f32 Xproj seeds proven harmless in rounds 2/5).
// ---------------------------------------------------------------------------
__global__ void __launch_bounds__(256) k1_xproj(
        const int* __restrict__ x, const float* __restrict__ emb,
        const float* __restrict__ Wf, const float* __restrict__ bf, const float* __restrict__ thf,
        const float* __restrict__ Wi, const float* __restrict__ bi, const float* __restrict__ thi,
        const float* __restrict__ Wu, const float* __restrict__ bu, const float* __restrict__ thu,
        const float* __restrict__ Wo, const float* __restrict__ bo, const float* __restrict__ tho,
        float* __restrict__ Xproj) {
    __shared__ __align__(16) float Wl[16][132];
    __shared__ float bl[16];
    const int tid = threadIdx.x;
    {
        const float* Wm[4] = {Wf, Wi, Wu, Wo};
        for (int idx = tid; idx < 16 * E; idx += 256) {
            int e = idx >> 4, q = idx & 15;
            int g = q & 3, j = q >> 2;
            Wl[q][e] = Wm[g][e * 4 + j];
        }
        if (tid < 16) {
            const float* bm[4] = {bf, bi, bu, bo};
            const float* tm[4] = {thf, thi, thu, tho};
            int g = tid & 3, j = tid >> 2;
            bl[tid] = bm[g][j] + tm[g][j];
        }
    }
    __syncthreads();
    const int T = blockIdx.x * 256 + tid;
    const int p = T >> 4, q = T & 15;
    if (p >= B * S) return;
    const float* row = emb + (size_t)x[p] * E;
    float acc = bl[q];
    #pragma unroll
    for (int e = 0; e < E; e += 4) {
        float4 wv = *(const float4*)(&Wl[q][e]);
        float4 ev = *(const float4*)(row + e);
        acc += ev.x * wv.x + ev.y * wv.y + ev.z * wv.z + ev.w * wv.w;
    }
    Xproj[(size_t)p * 16 + q] = acc;
}

// ---------------------------------------------------------------------------
// k2: sequential LSTM recurrence, all-f32 with HW transcendentals.
// 4 lanes per batch element (lane j = wire j).
//   Z0=c1c2c3, Z1=c0c1, Z2=c0c1c2, Z3=c0c1c2c3  (HW-verified rounds 2/5)
// Contractivity: |z|<=1 => f=sigma(z0)<=0.731 => per-step eps accumulates
// to <= eps/(1-0.731) ~ 3.7 eps; f32+HW-transcendental eps ~1e-6 => ~4e-6.
// hbuf layout: [B][S][4] (f32)
// ---------------------------------------------------------------------------
__global__ void __launch_bounds__(64) k2_recur(
        const float* __restrict__ Xproj,
        const float* __restrict__ Wf, const float* __restrict__ Wi,
        const float* __restrict__ Wu, const float* __restrict__ Wo,
        float* __restrict__ hbuf) {
    const int lane = threadIdx.x;
    const int T = blockIdx.x * 64 + lane;
    const int b = T >> 2, j = T & 3;

    // recurrent weights pre-permuted: hx register d holds hx_{(j+d)&3}
    const float* Wm[4] = {Wf, Wi, Wu, Wo};
    float w[4][4];
    #pragma unroll
    for (int g = 0; g < 4; ++g)
        #pragma unroll
        for (int d = 0; d < 4; ++d)
            w[g][d] = Wm[g][(E + ((j + d) & 3)) * 4 + j];

    // inclusion masks (lane-relative rotated regs); r3 always included.
    const bool m_own = (j != 0);
    const bool m_r1  = (j == 0) || (j == 3);
    const bool m_r2  = (j != 1);

    float hx0 = 0.f, hx1 = 0.f, hx2 = 0.f, hx3 = 0.f, cx = 0.f;

    const float4* xp4 = (const float4*)Xproj + (size_t)b * S * 4 + j; // [p*4+j]
    float* hout = hbuf + (size_t)b * S * 4 + j;

    float4 xp = xp4[0];
    for (int t = 0; t < S; ++t) {
        float4 xpn = xp4[(size_t)(t + 1 < S ? t + 1 : t) * 4];  // prefetch next step

        float pre0 = xp.x + w[0][0]*hx0 + w[0][1]*hx1 + w[0][2]*hx2 + w[0][3]*hx3;
        float pre1 = xp.y + w[1][0]*hx0 + w[1][1]*hx1 + w[1][2]*hx2 + w[1][3]*hx3;
        float pre2 = xp.z + w[2][0]*hx0 + w[2][1]*hx1 + w[2][2]*hx2 + w[2][3]*hx3;
        float pre3 = xp.w + w[3][0]*hx0 + w[3][1]*hx1 + w[3][2]*hx2 + w[3][3]*hx3;

        float c0 = __cosf(pre0);
        float c1 = __cosf(pre1);
        float c2 = __cosf(pre2);
        float c3 = __cosf(pre3);

        // shuffles hoisted, unconditional (ALL lanes execute every one)
        float a01 = rotf(c0, 1), a02 = rotf(c0, 2), a03 = rotf(c0, 3);
        float a11 = rotf(c1, 1), a12 = rotf(c1, 2), a13 = rotf(c1, 3);
        float a21 = rotf(c2, 1), a22 = rotf(c2, 2), a23 = rotf(c2, 3);
        float a31 = rotf(c3, 1), a32 = rotf(c3, 2), a33 = rotf(c3, 3);

        float z0 = (m_own ? c0 : 1.f) * (m_r1 ? a01 : 1.f) * (m_r2 ? a02 : 1.f) * a03;
        float z1 = (m_own ? c1 : 1.f) * (m_r1 ? a11 : 1.f) * (m_r2 ? a12 : 1.f) * a13;
        float z2 = (m_own ? c2 : 1.f) * (m_r1 ? a21 : 1.f) * (m_r2 ? a22 : 1.f) * a23;
        float z3 = (m_own ? c3 : 1.f) * (m_r1 ? a31 : 1.f) * (m_r2 ? a32 : 1.f) * a33;

        float f  = fsigmoid(z0);
        float i_ = fsigmoid(z1);
        float u  = ftanh(z2);
        float o  = fsigmoid(z3);

        cx = f * cx + i_ * u;
        float h = o * ftanh(cx);

        hout[(size_t)t * 4] = h;

        // hoisted, unconditional
        float h1 = rotf(h, 1), h2 = rotf(h, 2), h3 = rotf(h, 3);
        hx0 = h; hx1 = h1; hx2 = h2; hx3 = h3;
        xp = xpn;
    }
}

// ---------------------------------------------------------------------------
// k3: logits = hx @ Wt + bt, then log_softmax over the 10 tags, f64 internals.
// (verbatim from passing rounds 2/5 — zero-risk, ~10 us, off critical path)
// ---------------------------------------------------------------------------
__global__ void __launch_bounds__(256) k3_head(
        const float* __restrict__ hbuf, const float* __restrict__ Wt,
        const float* __restrict__ bt, float* __restrict__ out) {
    const int pos = blockIdx.x * 256 + threadIdx.x;
    if (pos >= B * S) return;
    float4 h = ((const float4*)hbuf)[pos];
    double h0 = h.x, h1 = h.y, h2 = h.z, h3 = h.w;
    double lo[NT];
    double m = -1e300;
    #pragma unroll
    for (int t = 0; t < NT; ++t) {
        lo[t] = (double)bt[t] + h0 * (double)Wt[t] + h1 * (double)Wt[NT + t]
              + h2 * (double)Wt[2 * NT + t] + h3 * (double)Wt[3 * NT + t];
        m = fmax(m, lo[t]);
    }
    double sum = 0.0;
    #pragma unroll
    for (int t = 0; t < NT; ++t) sum += exp(lo[t] - m);
    double lse = m + log(sum);
    float* op = out + (size_t)pos * NT;
    #pragma unroll
    for (int t = 0; t < NT; ++t) op[t] = (float)(lo[t] - lse);
}

extern "C" void kernel_launch(void* const* d_in, const int* in_sizes, int n_in,
                              void* d_out, int out_size, void* d_ws, size_t ws_size,
                              hipStream_t stream) {
    const int*   x   = (const int*)d_in[0];
    const float* emb = (const float*)d_in[1];
    const float* Wf  = (const float*)d_in[2];
    const float* bf  = (const float*)d_in[3];
    const float* thf = (const float*)d_in[4];
    const float* Wi  = (const float*)d_in[5];
    const float* bi  = (const float*)d_in[6];
    const float* thi = (const float*)d_in[7];
    const float* Wu  = (const float*)d_in[8];
    const float* bu  = (const float*)d_in[9];
    const float* thu = (const float*)d_in[10];
    const float* Wo  = (const float*)d_in[11];
    const float* bo  = (const float*)d_in[12];
    const float* tho = (const float*)d_in[13];
    const float* Wt  = (const float*)d_in[14];
    const float* bt  = (const float*)d_in[15];
    float* out = (float*)d_out;

    // workspace: Xproj [B*S*16] f32, then hbuf [B*S*4] f32
    if (ws_size < (size_t)(B * S * 20) * sizeof(float)) return;
    float* Xproj = (float*)d_ws;
    float* hbuf  = Xproj + (size_t)B * S * 16;

    k1_xproj<<<(B * S * 16) / 256, 256, 0, stream>>>(x, emb, Wf, bf, thf, Wi, bi, thi,
                                                     Wu, bu, thu, Wo, bo, tho, Xproj);
    k2_recur<<<(B * 4) / 64, 64, 0, stream>>>(Xproj, Wf, Wi, Wu, Wo, hbuf);
    k3_head<<<(B * S) / 256, 256, 0, stream>>>(hbuf, Wt, bt, out);
}

// Round 7
// 285.174 us; speedup vs baseline: 3.5805x; 1.1227x over previous
//
#include <hip/hip_runtime.h>
#include <math.h>

#define B 64
#define S 512
#define E 128
#define NT 10

// ---------------------------------------------------------------------------
// Quad rotation via DPP: lane j reads lane (j+d)&3 of its quad. 1 VALU op.
// CTRL: rot1=0x39 ([1,2,3,0]), rot2=0x4E ([2,3,0,1]), rot3=0x93 ([3,0,1,2]).
// RULE (HW-verified rounds 1/2/4/5/6): cross-lane ops MUST appear
// unconditionally in source (no lane-divergent ternary around the intrinsic);
// apply masks to the RESULT values. k2's loop body has zero control flow, so
// exec is full whenever these execute.
// ---------------------------------------------------------------------------
template<int CTRL>
__device__ __forceinline__ float rotq(float x) {
    return __int_as_float(__builtin_amdgcn_mov_dpp(__float_as_int(x), CTRL, 0xF, 0xF, true));
}

__device__ __forceinline__ float frcp(float x) { return __builtin_amdgcn_rcpf(x); }
__device__ __forceinline__ float fsigmoid(float x) { return frcp(1.0f + __expf(-x)); }
__device__ __forceinline__ float ftanh(float x) { return 1.0f - 2.0f * frcp(1.0f + __expf(2.0f * x)); }

// ---------------------------------------------------------------------------
// k1: Xproj[p][q] = sum_e emb[x[p]][e] * W_g[e][j] + b_g[j] + th_g[j]
//     p = b*S + s, q = j*4 + g  (g: 0=f,1=i,2=u,3=o; j = wire). all-f32.
//     (verbatim from passing round 6 — control variable this round)
// ---------------------------------------------------------------------------
__global__ void __launch_bounds__(256) k1_xproj(
        const int* __restrict__ x, const float* __restrict__ emb,
        const float* __restrict__ Wf, const float* __restrict__ bf, const float* __restrict__ thf,
        const float* __restrict__ Wi, const float* __restrict__ bi, const float* __restrict__ thi,
        const float* __restrict__ Wu, const float* __restrict__ bu, const float* __restrict__ thu,
        const float* __restrict__ Wo, const float* __restrict__ bo, const float* __restrict__ tho,
        float* __restrict__ Xproj) {
    __shared__ __align__(16) float Wl[16][132];
    __shared__ float bl[16];
    const int tid = threadIdx.x;
    {
        const float* Wm[4] = {Wf, Wi, Wu, Wo};
        for (int idx = tid; idx < 16 * E; idx += 256) {
            int e = idx >> 4, q = idx & 15;
            int g = q & 3, j = q >> 2;
            Wl[q][e] = Wm[g][e * 4 + j];
        }
        if (tid < 16) {
            const float* bm[4] = {bf, bi, bu, bo};
            const float* tm[4] = {thf, thi, thu, tho};
            int g = tid & 3, j = tid >> 2;
            bl[tid] = bm[g][j] + tm[g][j];
        }
    }
    __syncthreads();
    const int T = blockIdx.x * 256 + tid;
    const int p = T >> 4, q = T & 15;
    if (p >= B * S) return;
    const float* row = emb + (size_t)x[p] * E;
    float acc = bl[q];
    #pragma unroll
    for (int e = 0; e < E; e += 4) {
        float4 wv = *(const float4*)(&Wl[q][e]);
        float4 ev = *(const float4*)(row + e);
        acc += ev.x * wv.x + ev.y * wv.y + ev.z * wv.z + ev.w * wv.w;
    }
    Xproj[(size_t)p * 16 + q] = acc;
}

// ---------------------------------------------------------------------------
// k2: sequential LSTM recurrence, f32 + HW transcendentals + DPP rotations.
// 4 lanes per batch element (lane j = wire j).
//   Z0=c1c2c3, Z1=c0c1, Z2=c0c1c2, Z3=c0c1c2c3  (HW-verified rounds 2/5/6)
// hbuf layout: [B][S][4] (f32)
// ---------------------------------------------------------------------------
__global__ void __launch_bounds__(64) k2_recur(
        const float* __restrict__ Xproj,
        const float* __restrict__ Wf, const float* __restrict__ Wi,
        const float* __restrict__ Wu, const float* __restrict__ Wo,
        float* __restrict__ hbuf) {
    const int lane = threadIdx.x;
    const int T = blockIdx.x * 64 + lane;
    const int b = T >> 2, j = T & 3;

    // recurrent weights pre-permuted: hx register d holds hx_{(j+d)&3}
    const float* Wm[4] = {Wf, Wi, Wu, Wo};
    float w[4][4];
    #pragma unroll
    for (int g = 0; g < 4; ++g)
        #pragma unroll
        for (int d = 0; d < 4; ++d)
            w[g][d] = Wm[g][(E + ((j + d) & 3)) * 4 + j];

    // inclusion masks (lane-relative rotated regs); r3 always included.
    const bool m_own = (j != 0);
    const bool m_r1  = (j == 0) || (j == 3);
    const bool m_r2  = (j != 1);

    float hx0 = 0.f, hx1 = 0.f, hx2 = 0.f, hx3 = 0.f, cx = 0.f;

    const float4* xp4 = (const float4*)Xproj + (size_t)b * S * 4 + j; // [p*4+j]
    float* hout = hbuf + (size_t)b * S * 4 + j;

    float4 xp = xp4[0];
    for (int t = 0; t < S; ++t) {
        float4 xpn = xp4[(size_t)(t + 1 < S ? t + 1 : t) * 4];  // prefetch next step

        // manual trees to cut dependency depth (reassociation is fine:
        // error budget ~1e-6/step, contractive recurrence)
        float pre0 = fmaf(w[0][0], hx0, xp.x) + fmaf(w[0][1], hx1, w[0][2]*hx2 + w[0][3]*hx3);
        float pre1 = fmaf(w[1][0], hx0, xp.y) + fmaf(w[1][1], hx1, w[1][2]*hx2 + w[1][3]*hx3);
        float pre2 = fmaf(w[2][0], hx0, xp.z) + fmaf(w[2][1], hx1, w[2][2]*hx2 + w[2][3]*hx3);
        float pre3 = fmaf(w[3][0], hx0, xp.w) + fmaf(w[3][1], hx1, w[3][2]*hx2 + w[3][3]*hx3);

        float c0 = __cosf(pre0);
        float c1 = __cosf(pre1);
        float c2 = __cosf(pre2);
        float c3 = __cosf(pre3);

        // DPP rotations hoisted, unconditional
        float a01 = rotq<0x39>(c0), a02 = rotq<0x4E>(c0), a03 = rotq<0x93>(c0);
        float a11 = rotq<0x39>(c1), a12 = rotq<0x4E>(c1), a13 = rotq<0x93>(c1);
        float a21 = rotq<0x39>(c2), a22 = rotq<0x4E>(c2), a23 = rotq<0x93>(c2);
        float a31 = rotq<0x39>(c3), a32 = rotq<0x4E>(c3), a33 = rotq<0x93>(c3);

        // selects act on values only; balanced multiply trees
        float z0 = ((m_own ? c0 : 1.f) * (m_r1 ? a01 : 1.f)) * ((m_r2 ? a02 : 1.f) * a03);
        float z1 = ((m_own ? c1 : 1.f) * (m_r1 ? a11 : 1.f)) * ((m_r2 ? a12 : 1.f) * a13);
        float z2 = ((m_own ? c2 : 1.f) * (m_r1 ? a21 : 1.f)) * ((m_r2 ? a22 : 1.f) * a23);
        float z3 = ((m_own ? c3 : 1.f) * (m_r1 ? a31 : 1.f)) * ((m_r2 ? a32 : 1.f) * a33);

        float f  = fsigmoid(z0);
        float i_ = fsigmoid(z1);
        float u  = ftanh(z2);
        float o  = fsigmoid(z3);

        cx = fmaf(f, cx, i_ * u);
        float h = o * ftanh(cx);

        hout[(size_t)t * 4] = h;

        // DPP rotations hoisted, unconditional
        float h1 = rotq<0x39>(h), h2 = rotq<0x4E>(h), h3 = rotq<0x93>(h);
        hx0 = h; hx1 = h1; hx2 = h2; hx3 = h3;
        xp = xpn;
    }
}

// ---------------------------------------------------------------------------
// k3: logits = h @ Wt + bt, log_softmax over 10 tags. f32 + HW
// transcendentals — adds ~1e-6 error on a leaf computation; bf16-grid
// threshold is 0.0525. (was f64 libm: suspected ~100 us of hidden time)
// ---------------------------------------------------------------------------
__global__ void __launch_bounds__(256) k3_head(
        const float* __restrict__ hbuf, const float* __restrict__ Wt,
        const float* __restrict__ bt, float* __restrict__ out) {
    const int pos = blockIdx.x * 256 + threadIdx.x;
    if (pos >= B * S) return;
    float4 h = ((const float4*)hbuf)[pos];
    float lo[NT];
    float m = -1e30f;
    #pragma unroll
    for (int t = 0; t < NT; ++t) {
        lo[t] = bt[t] + h.x * Wt[t] + h.y * Wt[NT + t] + h.z * Wt[2 * NT + t] + h.w * Wt[3 * NT + t];
        m = fmaxf(m, lo[t]);
    }
    float sum = 0.f;
    #pragma unroll
    for (int t = 0; t < NT; ++t) sum += __expf(lo[t] - m);
    float lse = m + __logf(sum);
    float* op = out + (size_t)pos * NT;
    #pragma unroll
    for (int t = 0; t < NT; ++t) op[t] = lo[t] - lse;
}

extern "C" void kernel_launch(void* const* d_in, const int* in_sizes, int n_in,
                              void* d_out, int out_size, void* d_ws, size_t ws_size,
                              hipStream_t stream) {
    const int*   x   = (const int*)d_in[0];
    const float* emb = (const float*)d_in[1];
    const float* Wf  = (const float*)d_in[2];
    const float* bf  = (const float*)d_in[3];
    const float* thf = (const float*)d_in[4];
    const float* Wi  = (const float*)d_in[5];
    const float* bi  = (const float*)d_in[6];
    const float* thi = (const float*)d_in[7];
    const float* Wu  = (const float*)d_in[8];
    const float* bu  = (const float*)d_in[9];
    const float* thu = (const float*)d_in[10];
    const float* Wo  = (const float*)d_in[11];
    const float* bo  = (const float*)d_in[12];
    const float* tho = (const float*)d_in[13];
    const float* Wt  = (const float*)d_in[14];
    const float* bt  = (const float*)d_in[15];
    float* out = (float*)d_out;

    // workspace: Xproj [B*S*16] f32, then hbuf [B*S*4] f32
    if (ws_size < (size_t)(B * S * 20) * sizeof(float)) return;
    float* Xproj = (float*)d_ws;
    float* hbuf  = Xproj + (size_t)B * S * 16;

    k1_xproj<<<(B * S * 16) / 256, 256, 0, stream>>>(x, emb, Wf, bf, thf, Wi, bi, thi,
                                                     Wu, bu, thu, Wo, bo, tho, Xproj);
    k2_recur<<<(B * 4) / 64, 64, 0, stream>>>(Xproj, Wf, Wi, Wu, Wo, hbuf);
    k3_head<<<(B * S) / 256, 256, 0, stream>>>(hbuf, Wt, bt, out);
}